// Round 13
// baseline (182.640 us; speedup 1.0000x reference)
//
#include <hip/hip_runtime.h>

// InfluenceEncoder FUSED, MLP-explicit: B=4096, N=257, D=16, H=128.
// 1024 blocks x 256 thr (4 waves); wave = ONE FULL batch (256 agents) in two
// 128-agent chunks, straight-line code, all load buffers NAMED float4s:
//   prologue: issue chunk0 (tiles 0-3) + half of chunk1 (tiles 4,5);
//   weights(chunk0) from regs -> wave-private LDS (barrier-free);
//   cvt chunk0; issue tiles 6,7 (overlap w/ MFMA); MFMA+postproc chunk0;
//   weights(chunk1) (vmcnt waits only on t4-t7); cvt; MFMA+postproc chunk1.
// Postproc: relu-bias fold relu(e+b)=max(e,-b)+b; xor32 combine; wsum
// butterfly; ragg=relu(pacc*inv+bfc) f16 -> LDS; barrier; phase 2: wave wv
// -> cols [32wv,32wv+32), 2x4 mfma_f32_16x16x32_f16 vs Wagg^T, rows = 4
// batches (duplicated mod 4), store lq==0.
// REGISTER THEORY (R12 post-mortem): allocator squeezed every build to <=64
// arch-VGPRs and sank loads next to uses -> serial latency chains. (3,3)
// gives a ~170-reg budget so the hoisted loads can actually stay in flight.

typedef _Float16 half_t;
typedef half_t f16x8 __attribute__((ext_vector_type(8)));
typedef float f32x4 __attribute__((ext_vector_type(4)));
typedef float f32x16 __attribute__((ext_vector_type(16)));

__global__ __launch_bounds__(256)
__attribute__((amdgpu_waves_per_eu(3, 3)))
void fused_kernel(
    const float* __restrict__ x,     // [4096,257,16]
    const float* __restrict__ Wfc,   // [128,16]
    const float* __restrict__ bfc,   // [128]
    const float* __restrict__ Wagg,  // [128,128]
    const float* __restrict__ bagg,  // [128]
    float* __restrict__ out)         // [4096,128]
{
    const int t    = threadIdx.x;
    const int lane = t & 63;
    const int wv   = t >> 6;      // batch slot in block
    const int b0   = blockIdx.x * 4;
    const int b    = b0 + wv;
    const int lm   = lane & 31;   // row-in-tile (A) / col-in-tile (B,D)
    const int hi   = lane >> 5;   // k-octet

    __shared__ float  wls[4][128];   // per-wave weight slots (reused per chunk)
    __shared__ half_t ragg[4][136];  // relu(agg) f16 per batch slot, +pad

    const float* xb = x + (size_t)b * (257 * 16);
    auto rp = [&](int i) { return xb + (size_t)(1 + i * 32 + lm) * 16 + hi * 8; };

    // ---- prologue loads: chunk0 (t0-t3) + chunk1 first half (t4,t5) ----
    float4 t0a = *(const float4*)rp(0), t0b = *(const float4*)(rp(0) + 4);
    float4 t1a = *(const float4*)rp(1), t1b = *(const float4*)(rp(1) + 4);
    float4 t2a = *(const float4*)rp(2), t2b = *(const float4*)(rp(2) + 4);
    float4 t3a = *(const float4*)rp(3), t3b = *(const float4*)(rp(3) + 4);
    float4 t4a = *(const float4*)rp(4), t4b = *(const float4*)(rp(4) + 4);
    float4 t5a = *(const float4*)rp(5), t5b = *(const float4*)(rp(5) + 4);

    // ---- B-frags (Wfc) + folded -bias ----
    f16x8 bfr[4];
    float nb[4];
    #pragma unroll
    for (int ct = 0; ct < 4; ++ct) {
        const float* wp = Wfc + (size_t)(ct * 32 + lm) * 16 + hi * 8;
        const float4 w0 = *(const float4*)wp;
        const float4 w1 = *(const float4*)(wp + 4);
        bfr[ct] = (f16x8){(half_t)w0.x, (half_t)w0.y, (half_t)w0.z, (half_t)w0.w,
                          (half_t)w1.x, (half_t)w1.y, (half_t)w1.z, (half_t)w1.w};
        nb[ct] = -bfc[ct * 32 + lm];
    }
    const float2 ego = *(const float2*)xb;

    float wsum = 0.f;
    float pacc[4] = {0.f, 0.f, 0.f, 0.f};
    const f32x16 zc = {};

    auto weight = [&](int slot, const float4& va, const float4& vb) {
        if (hi == 0) {   // lo lanes hold k=0..7: x,y at 0,1; f6 at 6
            const float dx = va.x - ego.x, dy = va.y - ego.y;
            float w = 1.0f / (sqrtf(dx * dx + dy * dy) + 1.0f);
            if (vb.z == 1.0f) w *= 5.0f;
            wls[wv][slot * 32 + lm] = w;
            wsum += w;
        }
    };
    auto cvt = [](const float4& va, const float4& vb) {
        return (f16x8){(half_t)va.x, (half_t)va.y, (half_t)va.z, (half_t)va.w,
                       (half_t)vb.x, (half_t)vb.y, (half_t)vb.z, (half_t)vb.w};
    };
    auto mtile = [&](int slot, const f16x8& afr) {
        const float* wr = &wls[wv][slot * 32];
        const float4 w40 = *(const float4*)(wr + hi * 4);
        const float4 w41 = *(const float4*)(wr + 8 + hi * 4);
        const float4 w42 = *(const float4*)(wr + 16 + hi * 4);
        const float4 w43 = *(const float4*)(wr + 24 + hi * 4);
        const float4 w4[4] = {w40, w41, w42, w43};
        #pragma unroll
        for (int ct = 0; ct < 4; ++ct) {
            const f32x16 d = __builtin_amdgcn_mfma_f32_32x32x16_f16(afr, bfr[ct], zc, 0, 0, 0);
            // D: col=lane&31, row=(r&3)+8*(r>>2)+4*hi
            #pragma unroll
            for (int r = 0; r < 16; ++r)
                pacc[ct] = fmaf(w4[r >> 2][r & 3], fmaxf(d[r], nb[ct]), pacc[ct]);
        }
    };

    // ---- chunk 0 ----
    weight(0, t0a, t0b); weight(1, t1a, t1b);
    weight(2, t2a, t2b); weight(3, t3a, t3b);
    const f16x8 af0 = cvt(t0a, t0b), af1 = cvt(t1a, t1b);
    const f16x8 af2 = cvt(t2a, t2b), af3 = cvt(t3a, t3b);

    // chunk1 second half — issue before chunk0 compute to overlap
    float4 t6a = *(const float4*)rp(6), t6b = *(const float4*)(rp(6) + 4);
    float4 t7a = *(const float4*)rp(7), t7b = *(const float4*)(rp(7) + 4);

    mtile(0, af0); mtile(1, af1); mtile(2, af2); mtile(3, af3);

    // ---- chunk 1 (wls slots reused; same-wave DS ordering protects) ----
    weight(0, t4a, t4b); weight(1, t5a, t5b);
    weight(2, t6a, t6b); weight(3, t7a, t7b);
    const f16x8 af4 = cvt(t4a, t4b), af5 = cvt(t5a, t5b);
    const f16x8 af6 = cvt(t6a, t6b), af7 = cvt(t7a, t7b);

    mtile(0, af4); mtile(1, af5); mtile(2, af6); mtile(3, af7);

    // ---- epilogue: combine k-octets, normalize, relu -> ragg ----
    #pragma unroll
    for (int ct = 0; ct < 4; ++ct) pacc[ct] += __shfl_xor(pacc[ct], 32);
    #pragma unroll
    for (int off = 32; off > 0; off >>= 1) wsum += __shfl_xor(wsum, off);
    const float inv = 1.0f / (wsum + 1e-10f);
    if (hi == 0) {
        #pragma unroll
        for (int ct = 0; ct < 4; ++ct)
            ragg[wv][ct * 32 + lm] = (half_t)fmaxf(fmaf(pacc[ct], inv, -nb[ct]), 0.f);
    }
    __syncthreads();

    // ---- phase 2: out(4x128) = ragg @ Wagg^T + bagg ----
    const int lr = lane & 15;
    const int lq = lane >> 4;
    #pragma unroll
    for (int ci = 0; ci < 2; ++ci) {
        const int col = wv * 32 + ci * 16 + lr;
        const float bb2 = bagg[col];
        f32x4 acc = (f32x4){bb2, bb2, bb2, bb2};
        const float* wrow = Wagg + (size_t)col * 128;
        #pragma unroll
        for (int kk = 0; kk < 4; ++kk) {
            const int k0 = kk * 32 + lq * 8;
            const f16x8 a = *(const f16x8*)(&ragg[lr & 3][k0]);  // rows repeat mod 4
            const float4 wg0 = *(const float4*)(wrow + k0);
            const float4 wg1 = *(const float4*)(wrow + k0 + 4);
            const f16x8 bf = (f16x8){(half_t)wg0.x, (half_t)wg0.y, (half_t)wg0.z, (half_t)wg0.w,
                                     (half_t)wg1.x, (half_t)wg1.y, (half_t)wg1.z, (half_t)wg1.w};
            acc = __builtin_amdgcn_mfma_f32_16x16x32_f16(a, bf, acc, 0, 0, 0);
        }
        // D: col=lane&15, row=lq*4+jj; rows 0-3 are the block's batches
        if (lq == 0) {
            #pragma unroll
            for (int jj = 0; jj < 4; ++jj)
                out[(size_t)(b0 + jj) * 128 + col] = acc[jj];
        }
    }
}

extern "C" void kernel_launch(void* const* d_in, const int* in_sizes, int n_in,
                              void* d_out, int out_size, void* d_ws, size_t ws_size,
                              hipStream_t stream) {
    const float* x    = (const float*)d_in[0];
    const float* Wfc  = (const float*)d_in[1];
    const float* bfc  = (const float*)d_in[2];
    const float* Wagg = (const float*)d_in[3];
    const float* bagg = (const float*)d_in[4];
    float* out = (float*)d_out;

    fused_kernel<<<dim3(1024), dim3(256), 0, stream>>>(x, Wfc, bfc, Wagg, bagg, out);
}